// Round 1
// baseline (2718.542 us; speedup 1.0000x reference)
//
#include <hip/hip_runtime.h>

// LocalAttention: P=7 window attention.
// x:[32,192,56,56] f32 -> out:[32,192,56,56] f32 + attn:[2048,8,49,49] f32
// Round 0: correctness-first fp32 baseline, structured for later MFMA swap.

#define PW 7
#define NT 49          // PW*PW tokens per window
#define HEADS 8
#define DH 32
#define CIN 192
#define INNER 256      // HEADS*DH
#define HW 56
#define NWIN 2048      // 32 * 8 * 8 windows
#define OUT0 19267584  // 32*192*56*56

__global__ __launch_bounds__(256) void la_attn_kernel(
    const float* __restrict__ x, const float* __restrict__ mask,
    const float* __restrict__ Wq, const float* __restrict__ Wkv,
    const float* __restrict__ pos, float* __restrict__ attn_out,
    float* __restrict__ o_ws)
{
    __shared__ float sX[CIN][52];   // x window, [c][t], pad 52
    __shared__ float sQ[NT][33];    // q^T [t][d]
    __shared__ float sK[NT][33];    // k^T [t][d]
    __shared__ float sV[NT][33];    // v^T [t][d]
    __shared__ float sS[NT][53];    // scores/attn [i][j], pad 53 (stride 21 mod 32 -> conflict-free col reads)
    __shared__ float sB[NT][52];    // bias [i][j]

    const int tid = threadIdx.x;
    const int widx = blockIdx.x;
    const int bi = widx >> 6;
    const int w1 = (widx >> 3) & 7;
    const int w2 = widx & 7;
    const long xbase = (long)bi * CIN * HW * HW + (w1 * PW) * HW + (w2 * PW);

    // ---- Phase A: gather window into LDS + build bias table ----
    for (int idx = tid; idx < CIN * NT; idx += 256) {
        int c = idx / NT, t = idx - c * NT;
        sX[c][t] = x[xbase + c * (HW * HW) + (t / PW) * HW + (t % PW)];
    }
    for (int idx = tid; idx < NT * NT; idx += 256) {
        int i = idx / NT, j = idx - i * NT;
        int r0 = j / PW - i / PW + (PW - 1);
        int r1 = j % PW - i % PW + (PW - 1);
        sB[i][j] = mask[idx] + pos[r0 * 13 + r1];
    }
    __syncthreads();

    const float scale = 0.17677669529663687f;  // 32^-0.5

    for (int h = 0; h < HEADS; ++h) {
        // ---- Phase B: q,k,v projections for this head (transposed store [t][e]) ----
        for (int o = tid; o < 3 * DH * NT; o += 256) {
            int m = o / (DH * NT);
            int r = o - m * (DH * NT);
            int e = r / NT, t = r - e * NT;
            const float* wrow = (m == 0) ? (Wq + (h * DH + e) * CIN)
                              : (m == 1) ? (Wkv + (h * DH + e) * CIN)
                                         : (Wkv + (INNER + h * DH + e) * CIN);
            const float4* w4 = (const float4*)wrow;
            float acc = 0.f;
            #pragma unroll 8
            for (int c4 = 0; c4 < CIN / 4; ++c4) {
                float4 w = w4[c4];
                int c = c4 * 4;
                acc += w.x * sX[c][t] + w.y * sX[c + 1][t]
                     + w.z * sX[c + 2][t] + w.w * sX[c + 3][t];
            }
            if (m == 0)      sQ[t][e] = acc;
            else if (m == 1) sK[t][e] = acc;
            else             sV[t][e] = acc;
        }
        __syncthreads();

        // ---- Phase C: dots = scale*q.k^T + bias ----
        for (int o = tid; o < NT * NT; o += 256) {
            int i = o / NT, j = o - i * NT;
            float acc = 0.f;
            #pragma unroll
            for (int d = 0; d < DH; ++d) acc += sQ[i][d] * sK[j][d];
            sS[i][j] = acc * scale + sB[i][j];
        }
        __syncthreads();

        // ---- softmax per row (49 rows, one thread each; simple for round 0) ----
        if (tid < NT) {
            float rmax = -1e30f;
            for (int j = 0; j < NT; ++j) rmax = fmaxf(rmax, sS[tid][j]);
            float s = 0.f;
            for (int j = 0; j < NT; ++j) {
                float e = __expf(sS[tid][j] - rmax);
                sS[tid][j] = e;
                s += e;
            }
            float inv = 1.0f / s;
            for (int j = 0; j < NT; ++j) sS[tid][j] *= inv;
        }
        __syncthreads();

        // ---- write attn output [widx][h][i][j] ----
        float* abase = attn_out + ((long)(widx * HEADS + h)) * NT * NT;
        for (int o = tid; o < NT * NT; o += 256) {
            abase[o] = sS[o / NT][o - (o / NT) * NT];
        }

        // ---- Phase D: o = attn @ v, store to ws as [e][t] ----
        float* obase = o_ws + (long)widx * INNER * NT + h * DH * NT;
        for (int o = tid; o < DH * NT; o += 256) {
            int i = o % NT, d = o / NT;   // lanes: consecutive i -> coalesced store
            float acc = 0.f;
            #pragma unroll
            for (int j = 0; j < NT; ++j) acc += sS[i][j] * sV[j][d];
            obase[d * NT + i] = acc;
        }
        __syncthreads();  // protect sQ/sK/sV/sS before next head
    }
}

__global__ __launch_bounds__(256) void la_proj_kernel(
    const float* __restrict__ o_ws, const float* __restrict__ Wo,
    const float* __restrict__ bo, float* __restrict__ out)
{
    __shared__ float sO[INNER][52];
    const int tid = threadIdx.x;
    const int widx = blockIdx.x;
    const int bi = widx >> 6;
    const int w1 = (widx >> 3) & 7;
    const int w2 = widx & 7;

    const float* ob = o_ws + (long)widx * INNER * NT;
    for (int idx = tid; idx < INNER * NT; idx += 256) {
        int e = idx / NT, t = idx - e * NT;
        sO[e][t] = ob[idx];
    }
    __syncthreads();

    const long obase = (long)bi * CIN * HW * HW + (w1 * PW) * HW + (w2 * PW);
    for (int o = tid; o < CIN * NT; o += 256) {
        int oc = o / NT, t = o - (o / NT) * NT;
        const float4* w4 = (const float4*)(Wo + oc * INNER);
        float acc = bo[oc];
        #pragma unroll 8
        for (int e4 = 0; e4 < INNER / 4; ++e4) {
            float4 w = w4[e4];
            int e = e4 * 4;
            acc += w.x * sO[e][t] + w.y * sO[e + 1][t]
                 + w.z * sO[e + 2][t] + w.w * sO[e + 3][t];
        }
        out[obase + oc * (HW * HW) + (t / PW) * HW + (t % PW)] = acc;
    }
}

extern "C" void kernel_launch(void* const* d_in, const int* in_sizes, int n_in,
                              void* d_out, int out_size, void* d_ws, size_t ws_size,
                              hipStream_t stream)
{
    const float* x    = (const float*)d_in[0];
    const float* mask = (const float*)d_in[1];
    const float* Wq   = (const float*)d_in[2];
    const float* Wkv  = (const float*)d_in[3];
    const float* Wo   = (const float*)d_in[4];
    const float* bo   = (const float*)d_in[5];
    const float* pos  = (const float*)d_in[6];

    float* out  = (float*)d_out;
    float* attn = out + (long)OUT0;
    float* o_ws = (float*)d_ws;  // needs NWIN*INNER*NT*4 = 102,760,448 B of scratch

    la_attn_kernel<<<NWIN, 256, 0, stream>>>(x, mask, Wq, Wkv, pos, attn, o_ws);
    la_proj_kernel<<<NWIN, 256, 0, stream>>>(o_ws, Wo, bo, out);
}